// Round 20
// baseline (208.926 us; speedup 1.0000x reference)
//
#include <hip/hip_runtime.h>
#include <hip/hip_fp16.h>

#ifndef F1
#define F1 64
#define F2 32
#endif

#define NBLK 512     // blocks for scatter pass
#define BSH  7       // bucket = dst >> 7  (128 nodes per bucket)
#define BNODES 128
#define CAP  5120    // fixed per-bucket capacity (mean 4096, sigma 64 -> 16 sigma)
#define CHMAX 6272   // max edges per scatter block (CH for E=3.2M is 6252)

typedef _Float16 half8 __attribute__((ext_vector_type(8)));
typedef float floatx4 __attribute__((ext_vector_type(4)));

// ---------------- prep0: zero out[0] + bucket counters ----------------

__global__ __launch_bounds__(256) void prep0_kernel(float* __restrict__ out,
                                                    int* __restrict__ cnt, int NB) {
    if (threadIdx.x == 0) out[0] = 0.f;
    for (int i = threadIdx.x; i < NB; i += 256) cnt[i] = 0;
}

// ---------------- fused hist + reservation + LDS sort + coalesced scatter ----------------

__global__ __launch_bounds__(256) void scatter_sorted3(const int* __restrict__ src,
                                                       const int* __restrict__ dst,
                                                       int* __restrict__ cnt,
                                                       int* __restrict__ buck,
                                                       const float* __restrict__ W1,
                                                       const float* __restrict__ W2,
                                                       __half* __restrict__ W1t,
                                                       __half* __restrict__ W2t,
                                                       int E, int CH, int NB) {
    int b = blockIdx.x;
    int tid = threadIdx.x;
    if (b == NBLK) {  // weight prep: Wt[n][k] = half(W[k][n])
        for (int e = tid; e < 64 * 256; e += 256) {
            int n = e >> 8, k = e & 255;
            W1t[e] = __float2half(W1[k * 64 + n]);
        }
        for (int e = tid; e < 32 * 64; e += 256) {
            int n = e >> 6, k = e & 63;
            W2t[e] = __float2half(W2[k * 32 + n]);
        }
        return;
    }
    __shared__ int gbase[1024];
    __shared__ int lhist[1024];
    __shared__ int sc[1024];
    __shared__ int lcur[1024];
    __shared__ int sorted[CHMAX];
    __shared__ unsigned short sbkt[CHMAX];
    for (int i = tid; i < 1024; i += 256) lhist[i] = 0;
    __syncthreads();
    int start = b * CH, end = min(E, start + CH);
    int count = end - start;
    for (int e0 = start + tid * 4; e0 < end; e0 += 1024) {
        if (e0 + 4 <= end) {
            int4 d4 = *reinterpret_cast<const int4*>(dst + e0);
            atomicAdd(&lhist[d4.x >> BSH], 1);
            atomicAdd(&lhist[d4.y >> BSH], 1);
            atomicAdd(&lhist[d4.z >> BSH], 1);
            atomicAdd(&lhist[d4.w >> BSH], 1);
        } else {
            for (int e = e0; e < end; ++e) atomicAdd(&lhist[dst[e] >> BSH], 1);
        }
    }
    __syncthreads();
    for (int i = tid; i < 1024; i += 256) {
        int c = lhist[i];
        gbase[i] = (i < NB && c > 0) ? (i * CAP + atomicAdd(&cnt[i], c)) : 0;
        sc[i] = c;
    }
    __syncthreads();
    for (int ofs = 1; ofs < 1024; ofs <<= 1) {
        int i1 = tid + 256, i2 = tid + 512, i3 = tid + 768;
        int v0 = (tid >= ofs) ? sc[tid - ofs] : 0;
        int v1 = (i1 >= ofs) ? sc[i1 - ofs] : 0;
        int v2 = (i2 >= ofs) ? sc[i2 - ofs] : 0;
        int v3 = (i3 >= ofs) ? sc[i3 - ofs] : 0;
        __syncthreads();
        sc[tid] += v0; sc[i1] += v1; sc[i2] += v2; sc[i3] += v3;
        __syncthreads();
    }
    for (int i = tid; i < 1024; i += 256) {
        int ex = sc[i] - lhist[i];
        sc[i] = ex;
        lcur[i] = ex;
    }
    __syncthreads();
    for (int e0 = start + tid * 4; e0 < end; e0 += 1024) {
        if (e0 + 4 <= end) {
            int4 s4 = *reinterpret_cast<const int4*>(src + e0);
            int4 d4 = *reinterpret_cast<const int4*>(dst + e0);
            int k0 = d4.x >> BSH, p0 = atomicAdd(&lcur[k0], 1);
            sorted[p0] = (s4.x << BSH) | (d4.x & (BNODES - 1)); sbkt[p0] = (unsigned short)k0;
            int k1 = d4.y >> BSH, p1 = atomicAdd(&lcur[k1], 1);
            sorted[p1] = (s4.y << BSH) | (d4.y & (BNODES - 1)); sbkt[p1] = (unsigned short)k1;
            int k2 = d4.z >> BSH, p2 = atomicAdd(&lcur[k2], 1);
            sorted[p2] = (s4.z << BSH) | (d4.z & (BNODES - 1)); sbkt[p2] = (unsigned short)k2;
            int k3 = d4.w >> BSH, p3 = atomicAdd(&lcur[k3], 1);
            sorted[p3] = (s4.w << BSH) | (d4.w & (BNODES - 1)); sbkt[p3] = (unsigned short)k3;
        } else {
            for (int e = e0; e < end; ++e) {
                int d = dst[e];
                int k = d >> BSH, p = atomicAdd(&lcur[k], 1);
                sorted[p] = (src[e] << BSH) | (d & (BNODES - 1)); sbkt[p] = (unsigned short)k;
            }
        }
    }
    __syncthreads();
    for (int p = tid; p < count; p += 256) {
        int k = sbkt[p];
        buck[gbase[k] + (p - sc[k])] = sorted[p];
    }
}

// Per-bucket: degree count -> LDS exclusive scan -> row_off/deg/dinv -> csr fill.

__global__ __launch_bounds__(256) void bucket_deg_fill2(const int* __restrict__ buck,
                                                        const int* __restrict__ cnt,
                                                        int* __restrict__ deg,
                                                        float* __restrict__ dinv,
                                                        int* __restrict__ row_off,
                                                        int* __restrict__ csr,
                                                        int N, int NB) {
    __shared__ int bcnt[BNODES];
    __shared__ int sc[BNODES];
    __shared__ int lrow[BNODES];
    __shared__ int lcur[BNODES];
    int k = blockIdx.x;
    int tid = threadIdx.x;
    if (tid < BNODES) { bcnt[tid] = 0; lcur[tid] = 0; }
    __syncthreads();
    int bs = k * CAP;
    int be = bs + cnt[k];
    for (int e = bs + tid; e < be; e += 256)
        atomicAdd(&bcnt[buck[e] & (BNODES - 1)], 1);
    __syncthreads();
    if (tid < BNODES) sc[tid] = bcnt[tid];
    __syncthreads();
    for (int ofs = 1; ofs < BNODES; ofs <<= 1) {
        int v = (tid >= ofs && tid < BNODES) ? sc[tid - ofs] : 0;
        __syncthreads();
        if (tid < BNODES) sc[tid] += v;
        __syncthreads();
    }
    if (tid < BNODES) {
        int excl = sc[tid] - bcnt[tid];
        lrow[tid] = bs + excl;
        int i = (k << BSH) + tid;
        if (i < N) {
            deg[i] = bcnt[tid];
            dinv[i] = rsqrtf((float)(bcnt[tid] + 1));  // +1 self loop
            row_off[i] = bs + excl;
        }
    }
    __syncthreads();
    for (int e = bs + tid; e < be; e += 256) {
        int p = buck[e];
        int li = p & (BNODES - 1);
        int pos = lrow[li] + atomicAdd(&lcur[li], 1);
        csr[pos] = p >> BSH;
    }
}

// ---------------- MFMA GEMM (layer 1): g1 = half((x @ W1) * dinv) ----------------

__device__ __forceinline__ int swz(int p, int r) { return (p ^ ((r >> 1) & 3)) << 4; }

template <bool AF32, int K, int BN>
__global__ __launch_bounds__(256) void gemm_mfma_kernel(const void* __restrict__ Aptr,
                                                        const __half* __restrict__ Bt,
                                                        const float* __restrict__ dinv,
                                                        __half* __restrict__ C,
                                                        int M) {
    constexpr int NT = BN / 16;
    __shared__ half8 Ash[64 * 4];
    __shared__ half8 Bsh[BN * 4];
    char* Ab = (char*)Ash;
    char* Bb = (char*)Bsh;
    int tid = threadIdx.x;
    int w = tid >> 6;
    int l = tid & 63;
    int row0 = blockIdx.x * 64;
    int sr = tid >> 2, sp = tid & 3;
    int fr = l & 15, fp = l >> 4;
    int arow = w * 16 + fr;
    int a_off = arow * 64 + swz(fp, arow);

    floatx4 acc[NT];
#pragma unroll
    for (int c = 0; c < NT; ++c) acc[c] = (floatx4){0.f, 0.f, 0.f, 0.f};

    for (int k0 = 0; k0 < K; k0 += 32) {
        half8 av = {};
        int gr = row0 + sr;
        if (gr < M) {
            if constexpr (AF32) {
                const float* A = (const float*)Aptr;
                float4 f0 = *(const float4*)(A + (size_t)gr * K + k0 + sp * 8);
                float4 f1 = *(const float4*)(A + (size_t)gr * K + k0 + sp * 8 + 4);
                av[0] = (_Float16)f0.x; av[1] = (_Float16)f0.y;
                av[2] = (_Float16)f0.z; av[3] = (_Float16)f0.w;
                av[4] = (_Float16)f1.x; av[5] = (_Float16)f1.y;
                av[6] = (_Float16)f1.z; av[7] = (_Float16)f1.w;
            } else {
                const __half* A = (const __half*)Aptr;
                av = *(const half8*)(A + (size_t)gr * K + k0 + sp * 8);
            }
        }
        *(half8*)(Ab + sr * 64 + swz(sp, sr)) = av;
        if (tid < BN * 4) {
            int n = tid >> 2, p = tid & 3;
            half8 bv = *(const half8*)(Bt + (size_t)n * K + k0 + p * 8);
            *(half8*)(Bb + n * 64 + swz(p, n)) = bv;
        }
        __syncthreads();
        half8 a = *(const half8*)(Ab + a_off);
#pragma unroll
        for (int c = 0; c < NT; ++c) {
            int col = c * 16 + fr;
            half8 b = *(const half8*)(Bb + col * 64 + swz(fp, col));
            acc[c] = __builtin_amdgcn_mfma_f32_16x16x32_f16(a, b, acc[c], 0, 0, 0);
        }
        __syncthreads();
    }
#pragma unroll
    for (int i = 0; i < 4; ++i) {
        int r = row0 + w * 16 + fp * 4 + i;
        if (r < M) {
            float dn = dinv[r];
#pragma unroll
            for (int c = 0; c < NT; ++c)
                C[(size_t)r * BN + c * 16 + fr] = __float2half(acc[c][i] * dn);
        }
    }
}

// ---------------- gather helpers ----------------

__device__ __forceinline__ void acc_row16(const __half* __restrict__ base, float* a) {
    uint4 raw = *reinterpret_cast<const uint4*>(base);
    float2 f0 = __half22float2(*reinterpret_cast<const __half2*>(&raw.x));
    float2 f1 = __half22float2(*reinterpret_cast<const __half2*>(&raw.y));
    float2 f2 = __half22float2(*reinterpret_cast<const __half2*>(&raw.z));
    float2 f3 = __half22float2(*reinterpret_cast<const __half2*>(&raw.w));
    a[0] += f0.x; a[1] += f0.y; a[2] += f1.x; a[3] += f1.y;
    a[4] += f2.x; a[5] += f2.y; a[6] += f3.x; a[7] += f3.y;
}

__device__ __forceinline__ void acc_pk_raw(uint4 raw, __half2* c2) {
    c2[0] = __hadd2(c2[0], *reinterpret_cast<const __half2*>(&raw.x));
    c2[1] = __hadd2(c2[1], *reinterpret_cast<const __half2*>(&raw.y));
    c2[2] = __hadd2(c2[2], *reinterpret_cast<const __half2*>(&raw.z));
    c2[3] = __hadd2(c2[3], *reinterpret_cast<const __half2*>(&raw.w));
}

__device__ __forceinline__ void flush_pk(__half2* c2, float* a) {
#pragma unroll
    for (int j = 0; j < 4; ++j) {
        float2 f = __half22float2(c2[j]);
        a[2 * j] += f.x;
        a[2 * j + 1] += f.y;
        c2[j] = __float2half2_rn(0.f);
    }
}

// ---------------- Aggregation layer 1 + fused layer-2 MFMA GEMM ----------------
// 1024 threads = 16 waves = 16 nodes/block. Each wave gathers (8 edge-groups x
// 8 lanes x 16B, 4-deep superblock, pk-f16 chains) and writes its fp16 h1 row
// to LDS [16][72] (padded: 2-way bank alias = free). After one barrier, wave 0
// computes g2 rows for all 16 nodes with 4 mfma_f32_16x16x32_f16 — identical
// fragment pattern & k-order as the old gemm2, so g2 is bitwise unchanged.

__global__ __launch_bounds__(1024) void agg1_fused2(const __half* __restrict__ g1,
                                                    const int* __restrict__ row_off,
                                                    const int* __restrict__ deg,
                                                    const int* __restrict__ csr,
                                                    const float* __restrict__ dinv,
                                                    const float* __restrict__ b1,
                                                    const __half* __restrict__ W2t,
                                                    __half* __restrict__ g2, int n) {
    __shared__ __half h1sh[16][72];  // +8 pad: row stride 144B -> 2-way bank alias
    int tid = threadIdx.x;
    int wid = tid >> 6;
    int lane = tid & 63;
    int node = blockIdx.x * 16 + wid;
    int g = lane >> 3;        // edge group 0..7
    int f8 = lane & 7;        // 16B feature chunk 0..7
    float a[8];
#pragma unroll
    for (int j = 0; j < 8; ++j) a[j] = 0.f;
    if (node < n) {  // wave-uniform branch
        int start = row_off[node];
        int end = start + deg[node];
        if (g == 0)  // self loop counted once (f32 path)
            acc_row16(g1 + ((size_t)node << 6) + f8 * 8, a);
        __half2 c2[4];
#pragma unroll
        for (int j = 0; j < 4; ++j) c2[j] = __float2half2_rn(0.f);
        int e = start;
        for (; e + 32 <= end; e += 32) {  // 4 gathers in flight
            int i0 = csr[e + g];
            int i1 = csr[e + 8 + g];
            int i2 = csr[e + 16 + g];
            int i3 = csr[e + 24 + g];
            uint4 r0 = *reinterpret_cast<const uint4*>(g1 + ((size_t)i0 << 6) + f8 * 8);
            uint4 r1 = *reinterpret_cast<const uint4*>(g1 + ((size_t)i1 << 6) + f8 * 8);
            uint4 r2 = *reinterpret_cast<const uint4*>(g1 + ((size_t)i2 << 6) + f8 * 8);
            uint4 r3 = *reinterpret_cast<const uint4*>(g1 + ((size_t)i3 << 6) + f8 * 8);
            acc_pk_raw(r0, c2);
            acc_pk_raw(r1, c2);
            acc_pk_raw(r2, c2);
            acc_pk_raw(r3, c2);
            flush_pk(c2, a);  // <=4 fp16 adds per chain
        }
        if (e + 16 <= end) {  // 2-deep remainder
            int i0 = csr[e + g];
            int i1 = csr[e + 8 + g];
            uint4 r0 = *reinterpret_cast<const uint4*>(g1 + ((size_t)i0 << 6) + f8 * 8);
            uint4 r1 = *reinterpret_cast<const uint4*>(g1 + ((size_t)i1 << 6) + f8 * 8);
            acc_pk_raw(r0, c2);
            acc_pk_raw(r1, c2);
            e += 16;
        }
        if (e + 8 <= end) {
            int s = csr[e + g];
            uint4 r = *reinterpret_cast<const uint4*>(g1 + ((size_t)s << 6) + f8 * 8);
            acc_pk_raw(r, c2);
            e += 8;
        }
        if (e + g < end) {
            int s = csr[e + g];
            uint4 r = *reinterpret_cast<const uint4*>(g1 + ((size_t)s << 6) + f8 * 8);
            acc_pk_raw(r, c2);
        }
        flush_pk(c2, a);
        // fold 8 edge groups
#pragma unroll
        for (int j = 0; j < 8; ++j) a[j] += __shfl_xor(a[j], 8);
#pragma unroll
        for (int j = 0; j < 8; ++j) a[j] += __shfl_xor(a[j], 16);
#pragma unroll
        for (int j = 0; j < 8; ++j) a[j] += __shfl_xor(a[j], 32);
    }
    if (g == 0) {  // write fp16 h1 row to LDS (zeros for OOB nodes)
        __half hh[8];
        if (node < n) {
            float dn = dinv[node];
            float4 bl = *reinterpret_cast<const float4*>(b1 + f8 * 8);
            float4 bh = *reinterpret_cast<const float4*>(b1 + f8 * 8 + 4);
            hh[0] = __float2half(fmaxf(a[0] * dn + bl.x, 0.f));
            hh[1] = __float2half(fmaxf(a[1] * dn + bl.y, 0.f));
            hh[2] = __float2half(fmaxf(a[2] * dn + bl.z, 0.f));
            hh[3] = __float2half(fmaxf(a[3] * dn + bl.w, 0.f));
            hh[4] = __float2half(fmaxf(a[4] * dn + bh.x, 0.f));
            hh[5] = __float2half(fmaxf(a[5] * dn + bh.y, 0.f));
            hh[6] = __float2half(fmaxf(a[6] * dn + bh.z, 0.f));
            hh[7] = __float2half(fmaxf(a[7] * dn + bh.w, 0.f));
        } else {
#pragma unroll
            for (int j = 0; j < 8; ++j) hh[j] = __float2half(0.f);
        }
        *reinterpret_cast<uint4*>(&h1sh[wid][f8 * 8]) = *reinterpret_cast<const uint4*>(hh);
    }
    __syncthreads();
    // wave 0: g2[16 nodes][32] = half((h1 @ W2) * dinv) via 4 MFMAs
    if (tid < 64) {
        int fr = tid & 15, fp = tid >> 4;
        floatx4 acc0 = (floatx4){0.f, 0.f, 0.f, 0.f};
        floatx4 acc1 = (floatx4){0.f, 0.f, 0.f, 0.f};
#pragma unroll
        for (int k0 = 0; k0 < 64; k0 += 32) {
            half8 av = *reinterpret_cast<const half8*>(&h1sh[fr][k0 + fp * 8]);
            half8 b0 = *reinterpret_cast<const half8*>(W2t + (size_t)fr * 64 + k0 + fp * 8);
            half8 b1v = *reinterpret_cast<const half8*>(W2t + (size_t)(16 + fr) * 64 + k0 + fp * 8);
            acc0 = __builtin_amdgcn_mfma_f32_16x16x32_f16(av, b0, acc0, 0, 0, 0);
            acc1 = __builtin_amdgcn_mfma_f32_16x16x32_f16(av, b1v, acc1, 0, 0, 0);
        }
#pragma unroll
        for (int i = 0; i < 4; ++i) {
            int r = blockIdx.x * 16 + fp * 4 + i;
            if (r < n) {
                float dn = dinv[r];
                g2[(size_t)r * 32 + fr] = __float2half(acc0[i] * dn);
                g2[(size_t)r * 32 + 16 + fr] = __float2half(acc1[i] * dn);
            }
        }
    }
}

// ---------------- Aggregation layer 2 + pooling: HALF-wave per node ----------------

__global__ __launch_bounds__(256) void agg2_pool_kernel(const __half* __restrict__ g2,
                                                        const int* __restrict__ row_off,
                                                        const int* __restrict__ deg,
                                                        const int* __restrict__ csr,
                                                        const float* __restrict__ dinv,
                                                        const float* __restrict__ b2,
                                                        float* __restrict__ partials,
                                                        int nblocks, int n) {
    int tid = threadIdx.x;
    int half = tid >> 5;            // half-wave 0..7 in block
    int node = blockIdx.x * 8 + half;
    int l32 = tid & 31;
    int g = (l32 >> 2);             // edge group 0..7
    int f4 = l32 & 3;               // 16B feature chunk 0..3
    float a[8];
#pragma unroll
    for (int j = 0; j < 8; ++j) a[j] = 0.f;
    if (node < n) {
        int start = row_off[node];
        int end = start + deg[node];
        if (g == 0)
            acc_row16(g2 + ((size_t)node << 5) + f4 * 8, a);
        __half2 c2[4];
#pragma unroll
        for (int j = 0; j < 4; ++j) c2[j] = __float2half2_rn(0.f);
        int e = start;
        for (; e + 32 <= end; e += 32) {  // 4-deep
            int i0 = csr[e + g];
            int i1 = csr[e + 8 + g];
            int i2 = csr[e + 16 + g];
            int i3 = csr[e + 24 + g];
            uint4 r0 = *reinterpret_cast<const uint4*>(g2 + ((size_t)i0 << 5) + f4 * 8);
            uint4 r1 = *reinterpret_cast<const uint4*>(g2 + ((size_t)i1 << 5) + f4 * 8);
            uint4 r2 = *reinterpret_cast<const uint4*>(g2 + ((size_t)i2 << 5) + f4 * 8);
            uint4 r3 = *reinterpret_cast<const uint4*>(g2 + ((size_t)i3 << 5) + f4 * 8);
            acc_pk_raw(r0, c2);
            acc_pk_raw(r1, c2);
            acc_pk_raw(r2, c2);
            acc_pk_raw(r3, c2);
            flush_pk(c2, a);
        }
        if (e + 16 <= end) {  // 2-deep remainder
            int i0 = csr[e + g];
            int i1 = csr[e + 8 + g];
            uint4 r0 = *reinterpret_cast<const uint4*>(g2 + ((size_t)i0 << 5) + f4 * 8);
            uint4 r1 = *reinterpret_cast<const uint4*>(g2 + ((size_t)i1 << 5) + f4 * 8);
            acc_pk_raw(r0, c2);
            acc_pk_raw(r1, c2);
            e += 16;
        }
        if (e + 8 <= end) {
            int s = csr[e + g];
            uint4 r = *reinterpret_cast<const uint4*>(g2 + ((size_t)s << 5) + f4 * 8);
            acc_pk_raw(r, c2);
            e += 8;
        }
        if (e + g < end) {
            int s = csr[e + g];
            uint4 r = *reinterpret_cast<const uint4*>(g2 + ((size_t)s << 5) + f4 * 8);
            acc_pk_raw(r, c2);
        }
        flush_pk(c2, a);
#pragma unroll
        for (int j = 0; j < 8; ++j) a[j] += __shfl_xor(a[j], 4);
#pragma unroll
        for (int j = 0; j < 8; ++j) a[j] += __shfl_xor(a[j], 8);
#pragma unroll
        for (int j = 0; j < 8; ++j) a[j] += __shfl_xor(a[j], 16);
    }
    __shared__ float sdata[8][32];
    if (g == 0) {
        float relu[8];
        if (node < n) {
            float dn = dinv[node];
#pragma unroll
            for (int j = 0; j < 8; ++j)
                relu[j] = fmaxf(a[j] * dn + b2[f4 * 8 + j], 0.f);
        } else {
#pragma unroll
            for (int j = 0; j < 8; ++j) relu[j] = 0.f;
        }
#pragma unroll
        for (int j = 0; j < 8; ++j) sdata[half][f4 * 8 + j] = relu[j];
    }
    __syncthreads();
    if (tid < 32) {
        float s = 0.f;
#pragma unroll
        for (int r = 0; r < 8; ++r) s += sdata[r][tid];
        partials[tid * nblocks + blockIdx.x] = s;
    }
}

// 32 blocks, one per feature; fused FC: atomicAdd into pre-zeroed out[0].
__global__ __launch_bounds__(256) void reduce_fc_kernel(const float* __restrict__ partials,
                                                        int nblocks,
                                                        const float* __restrict__ fcw,
                                                        const float* __restrict__ fcb,
                                                        float* __restrict__ out, int n) {
    int f = blockIdx.x;
    const float* col = partials + (size_t)f * nblocks;
    float s = 0.f;
    for (int i = threadIdx.x; i < nblocks; i += 256) s += col[i];
    __shared__ float red[256];
    red[threadIdx.x] = s;
    __syncthreads();
    for (int ofs = 128; ofs > 0; ofs >>= 1) {
        if (threadIdx.x < ofs) red[threadIdx.x] += red[threadIdx.x + ofs];
        __syncthreads();
    }
    if (threadIdx.x == 0) {
        float v = (float)((double)red[0] / (double)n * (double)fcw[f]);
        if (f == 0) v += fcb[0];
        atomicAdd(out, v);
    }
}

// ---------------- launch ----------------

extern "C" void kernel_launch(void* const* d_in, const int* in_sizes, int n_in,
                              void* d_out, int out_size, void* d_ws, size_t ws_size,
                              hipStream_t stream) {
    const float* x   = (const float*)d_in[0];
    const int*   ei  = (const int*)d_in[1];
    const float* W1  = (const float*)d_in[2];
    const float* b1  = (const float*)d_in[3];
    const float* W2  = (const float*)d_in[4];
    const float* b2  = (const float*)d_in[5];
    const float* fcw = (const float*)d_in[6];
    const float* fcb = (const float*)d_in[7];
    float* out = (float*)d_out;

    const int N = in_sizes[0] / 256;  // 100000
    const int E = in_sizes[1] / 2;    // 3200000
    const int* src = ei;
    const int* dst = ei + E;

    const int NB = (N + BNODES - 1) >> BSH;            // 782 buckets
    const int CH = (((E + NBLK - 1) / NBLK) + 3) & ~3; // edges/block, x4 aligned (6252)
    const int nb2 = (N + 7) / 8;                       // agg2 blocks (8 nodes)
    const size_t CAPTOT = (size_t)NB * CAP;            // fixed-capacity layout size

    char* ws = (char*)d_ws;
    size_t off = 0;
    auto alloc = [&](size_t bytes) -> void* {
        void* p = ws + off;
        off = (off + bytes + 255) & ~(size_t)255;
        return p;
    };
    int*   cnt      = (int*)alloc((size_t)NB * 4);
    int*   row_off  = (int*)alloc((size_t)N * 4);
    int*   deg      = (int*)alloc((size_t)N * 4);
    float* dinv     = (float*)alloc((size_t)N * 4);
    int*   csr      = (int*)alloc(CAPTOT * 4);
    __half* W1t     = (__half*)alloc((size_t)64 * 256 * 2);
    __half* W2t     = (__half*)alloc((size_t)32 * 64 * 2);
    // region P: buck (CAPTOT int) aliases g1 (N*F1 halves) — buck dead before gemm1
    size_t szP = CAPTOT * 4;
    size_t szG1 = (size_t)N * F1 * 2;
    void* P = alloc(szP > szG1 ? szP : szG1);
    int*    buck = (int*)P;
    __half* g1   = (__half*)P;
    __half* g2      = (__half*)alloc((size_t)N * F2 * 2);
    float* partials = (float*)alloc((size_t)F2 * nb2 * 4);

    // ---- CSR build: 3 kernels (prep0, fused sorted scatter, deg/fill) ----
    prep0_kernel<<<1, 256, 0, stream>>>(out, cnt, NB);
    scatter_sorted3<<<NBLK + 1, 256, 0, stream>>>(src, dst, cnt, buck, W1, W2, W1t, W2t, E, CH, NB);
    bucket_deg_fill2<<<NB, 256, 0, stream>>>(buck, cnt, deg, dinv, row_off, csr, N, NB);

    int nbG = (N + 63) / 64;  // 1563
    // ---- layer 1 (+ fused layer-2 MFMA GEMM in epilogue) ----
    gemm_mfma_kernel<true, 256, 64><<<nbG, 256, 0, stream>>>(x, W1t, dinv, g1, N);
    agg1_fused2<<<(N + 15) / 16, 1024, 0, stream>>>(g1, row_off, deg, csr, dinv, b1, W2t, g2, N);

    // ---- layer 2 aggregation + pooling ----
    agg2_pool_kernel<<<nb2, 256, 0, stream>>>(g2, row_off, deg, csr, dinv, b2, partials, nb2, N);

    reduce_fc_kernel<<<F2, 256, 0, stream>>>(partials, nb2, fcw, fcb, out, N);
}

// Round 21
// 193.269 us; speedup vs baseline: 1.0810x; 1.0810x over previous
//
#include <hip/hip_runtime.h>
#include <hip/hip_fp16.h>

#ifndef F1
#define F1 64
#define F2 32
#endif

#define NBLK 512     // blocks for scatter pass
#define BSH  7       // bucket = dst >> 7  (128 nodes per bucket)
#define BNODES 128
#define CAP  5120    // fixed per-bucket capacity (mean 4096, sigma 64 -> 16 sigma)
#define CHMAX 6272   // max edges per scatter block (CH for E=3.2M is 6252)

typedef _Float16 half8 __attribute__((ext_vector_type(8)));
typedef float floatx4 __attribute__((ext_vector_type(4)));

// ---------------- prep0: zero out[0] + bucket counters ----------------

__global__ __launch_bounds__(256) void prep0_kernel(float* __restrict__ out,
                                                    int* __restrict__ cnt, int NB) {
    if (threadIdx.x == 0) out[0] = 0.f;
    for (int i = threadIdx.x; i < NB; i += 256) cnt[i] = 0;
}

// ---------------- fused hist + reservation + LDS sort + coalesced scatter ----------------

__global__ __launch_bounds__(256) void scatter_sorted3(const int* __restrict__ src,
                                                       const int* __restrict__ dst,
                                                       int* __restrict__ cnt,
                                                       int* __restrict__ buck,
                                                       const float* __restrict__ W1,
                                                       const float* __restrict__ W2,
                                                       __half* __restrict__ W1t,
                                                       __half* __restrict__ W2t,
                                                       int E, int CH, int NB) {
    int b = blockIdx.x;
    int tid = threadIdx.x;
    if (b == NBLK) {  // weight prep: Wt[n][k] = half(W[k][n])
        for (int e = tid; e < 64 * 256; e += 256) {
            int n = e >> 8, k = e & 255;
            W1t[e] = __float2half(W1[k * 64 + n]);
        }
        for (int e = tid; e < 32 * 64; e += 256) {
            int n = e >> 6, k = e & 63;
            W2t[e] = __float2half(W2[k * 32 + n]);
        }
        return;
    }
    __shared__ int gbase[1024];
    __shared__ int lhist[1024];
    __shared__ int sc[1024];
    __shared__ int lcur[1024];
    __shared__ int sorted[CHMAX];
    __shared__ unsigned short sbkt[CHMAX];
    for (int i = tid; i < 1024; i += 256) lhist[i] = 0;
    __syncthreads();
    int start = b * CH, end = min(E, start + CH);
    int count = end - start;
    for (int e0 = start + tid * 4; e0 < end; e0 += 1024) {
        if (e0 + 4 <= end) {
            int4 d4 = *reinterpret_cast<const int4*>(dst + e0);
            atomicAdd(&lhist[d4.x >> BSH], 1);
            atomicAdd(&lhist[d4.y >> BSH], 1);
            atomicAdd(&lhist[d4.z >> BSH], 1);
            atomicAdd(&lhist[d4.w >> BSH], 1);
        } else {
            for (int e = e0; e < end; ++e) atomicAdd(&lhist[dst[e] >> BSH], 1);
        }
    }
    __syncthreads();
    for (int i = tid; i < 1024; i += 256) {
        int c = lhist[i];
        gbase[i] = (i < NB && c > 0) ? (i * CAP + atomicAdd(&cnt[i], c)) : 0;
        sc[i] = c;
    }
    __syncthreads();
    for (int ofs = 1; ofs < 1024; ofs <<= 1) {
        int i1 = tid + 256, i2 = tid + 512, i3 = tid + 768;
        int v0 = (tid >= ofs) ? sc[tid - ofs] : 0;
        int v1 = (i1 >= ofs) ? sc[i1 - ofs] : 0;
        int v2 = (i2 >= ofs) ? sc[i2 - ofs] : 0;
        int v3 = (i3 >= ofs) ? sc[i3 - ofs] : 0;
        __syncthreads();
        sc[tid] += v0; sc[i1] += v1; sc[i2] += v2; sc[i3] += v3;
        __syncthreads();
    }
    for (int i = tid; i < 1024; i += 256) {
        int ex = sc[i] - lhist[i];
        sc[i] = ex;
        lcur[i] = ex;
    }
    __syncthreads();
    for (int e0 = start + tid * 4; e0 < end; e0 += 1024) {
        if (e0 + 4 <= end) {
            int4 s4 = *reinterpret_cast<const int4*>(src + e0);
            int4 d4 = *reinterpret_cast<const int4*>(dst + e0);
            int k0 = d4.x >> BSH, p0 = atomicAdd(&lcur[k0], 1);
            sorted[p0] = (s4.x << BSH) | (d4.x & (BNODES - 1)); sbkt[p0] = (unsigned short)k0;
            int k1 = d4.y >> BSH, p1 = atomicAdd(&lcur[k1], 1);
            sorted[p1] = (s4.y << BSH) | (d4.y & (BNODES - 1)); sbkt[p1] = (unsigned short)k1;
            int k2 = d4.z >> BSH, p2 = atomicAdd(&lcur[k2], 1);
            sorted[p2] = (s4.z << BSH) | (d4.z & (BNODES - 1)); sbkt[p2] = (unsigned short)k2;
            int k3 = d4.w >> BSH, p3 = atomicAdd(&lcur[k3], 1);
            sorted[p3] = (s4.w << BSH) | (d4.w & (BNODES - 1)); sbkt[p3] = (unsigned short)k3;
        } else {
            for (int e = e0; e < end; ++e) {
                int d = dst[e];
                int k = d >> BSH, p = atomicAdd(&lcur[k], 1);
                sorted[p] = (src[e] << BSH) | (d & (BNODES - 1)); sbkt[p] = (unsigned short)k;
            }
        }
    }
    __syncthreads();
    for (int p = tid; p < count; p += 256) {
        int k = sbkt[p];
        buck[gbase[k] + (p - sc[k])] = sorted[p];
    }
}

// Per-bucket: degree count -> LDS exclusive scan -> row_off/deg/dinv -> csr fill.

__global__ __launch_bounds__(256) void bucket_deg_fill2(const int* __restrict__ buck,
                                                        const int* __restrict__ cnt,
                                                        int* __restrict__ deg,
                                                        float* __restrict__ dinv,
                                                        int* __restrict__ row_off,
                                                        int* __restrict__ csr,
                                                        int N, int NB) {
    __shared__ int bcnt[BNODES];
    __shared__ int sc[BNODES];
    __shared__ int lrow[BNODES];
    __shared__ int lcur[BNODES];
    int k = blockIdx.x;
    int tid = threadIdx.x;
    if (tid < BNODES) { bcnt[tid] = 0; lcur[tid] = 0; }
    __syncthreads();
    int bs = k * CAP;
    int be = bs + cnt[k];
    for (int e = bs + tid; e < be; e += 256)
        atomicAdd(&bcnt[buck[e] & (BNODES - 1)], 1);
    __syncthreads();
    if (tid < BNODES) sc[tid] = bcnt[tid];
    __syncthreads();
    for (int ofs = 1; ofs < BNODES; ofs <<= 1) {
        int v = (tid >= ofs && tid < BNODES) ? sc[tid - ofs] : 0;
        __syncthreads();
        if (tid < BNODES) sc[tid] += v;
        __syncthreads();
    }
    if (tid < BNODES) {
        int excl = sc[tid] - bcnt[tid];
        lrow[tid] = bs + excl;
        int i = (k << BSH) + tid;
        if (i < N) {
            deg[i] = bcnt[tid];
            dinv[i] = rsqrtf((float)(bcnt[tid] + 1));  // +1 self loop
            row_off[i] = bs + excl;
        }
    }
    __syncthreads();
    for (int e = bs + tid; e < be; e += 256) {
        int p = buck[e];
        int li = p & (BNODES - 1);
        int pos = lrow[li] + atomicAdd(&lcur[li], 1);
        csr[pos] = p >> BSH;
    }
}

// ---------------- MFMA GEMM: C = half((A @ B) * dinv[row]) ----------------

__device__ __forceinline__ int swz(int p, int r) { return (p ^ ((r >> 1) & 3)) << 4; }

template <bool AF32, int K, int BN>
__global__ __launch_bounds__(256) void gemm_mfma_kernel(const void* __restrict__ Aptr,
                                                        const __half* __restrict__ Bt,
                                                        const float* __restrict__ dinv,
                                                        __half* __restrict__ C,
                                                        int M) {
    constexpr int NT = BN / 16;
    __shared__ half8 Ash[64 * 4];
    __shared__ half8 Bsh[BN * 4];
    char* Ab = (char*)Ash;
    char* Bb = (char*)Bsh;
    int tid = threadIdx.x;
    int w = tid >> 6;
    int l = tid & 63;
    int row0 = blockIdx.x * 64;
    int sr = tid >> 2, sp = tid & 3;
    int fr = l & 15, fp = l >> 4;
    int arow = w * 16 + fr;
    int a_off = arow * 64 + swz(fp, arow);

    floatx4 acc[NT];
#pragma unroll
    for (int c = 0; c < NT; ++c) acc[c] = (floatx4){0.f, 0.f, 0.f, 0.f};

    for (int k0 = 0; k0 < K; k0 += 32) {
        half8 av = {};
        int gr = row0 + sr;
        if (gr < M) {
            if constexpr (AF32) {
                const float* A = (const float*)Aptr;
                float4 f0 = *(const float4*)(A + (size_t)gr * K + k0 + sp * 8);
                float4 f1 = *(const float4*)(A + (size_t)gr * K + k0 + sp * 8 + 4);
                av[0] = (_Float16)f0.x; av[1] = (_Float16)f0.y;
                av[2] = (_Float16)f0.z; av[3] = (_Float16)f0.w;
                av[4] = (_Float16)f1.x; av[5] = (_Float16)f1.y;
                av[6] = (_Float16)f1.z; av[7] = (_Float16)f1.w;
            } else {
                const __half* A = (const __half*)Aptr;
                av = *(const half8*)(A + (size_t)gr * K + k0 + sp * 8);
            }
        }
        *(half8*)(Ab + sr * 64 + swz(sp, sr)) = av;
        if (tid < BN * 4) {
            int n = tid >> 2, p = tid & 3;
            half8 bv = *(const half8*)(Bt + (size_t)n * K + k0 + p * 8);
            *(half8*)(Bb + n * 64 + swz(p, n)) = bv;
        }
        __syncthreads();
        half8 a = *(const half8*)(Ab + a_off);
#pragma unroll
        for (int c = 0; c < NT; ++c) {
            int col = c * 16 + fr;
            half8 b = *(const half8*)(Bb + col * 64 + swz(fp, col));
            acc[c] = __builtin_amdgcn_mfma_f32_16x16x32_f16(a, b, acc[c], 0, 0, 0);
        }
        __syncthreads();
    }
#pragma unroll
    for (int i = 0; i < 4; ++i) {
        int r = row0 + w * 16 + fp * 4 + i;
        if (r < M) {
            float dn = dinv[r];
#pragma unroll
            for (int c = 0; c < NT; ++c)
                C[(size_t)r * BN + c * 16 + fr] = __float2half(acc[c][i] * dn);
        }
    }
}

// ---------------- gather helpers ----------------

__device__ __forceinline__ void acc_row16(const __half* __restrict__ base, float* a) {
    uint4 raw = *reinterpret_cast<const uint4*>(base);
    float2 f0 = __half22float2(*reinterpret_cast<const __half2*>(&raw.x));
    float2 f1 = __half22float2(*reinterpret_cast<const __half2*>(&raw.y));
    float2 f2 = __half22float2(*reinterpret_cast<const __half2*>(&raw.z));
    float2 f3 = __half22float2(*reinterpret_cast<const __half2*>(&raw.w));
    a[0] += f0.x; a[1] += f0.y; a[2] += f1.x; a[3] += f1.y;
    a[4] += f2.x; a[5] += f2.y; a[6] += f3.x; a[7] += f3.y;
}

__device__ __forceinline__ void acc_pk_raw(uint4 raw, __half2* c2) {
    c2[0] = __hadd2(c2[0], *reinterpret_cast<const __half2*>(&raw.x));
    c2[1] = __hadd2(c2[1], *reinterpret_cast<const __half2*>(&raw.y));
    c2[2] = __hadd2(c2[2], *reinterpret_cast<const __half2*>(&raw.z));
    c2[3] = __hadd2(c2[3], *reinterpret_cast<const __half2*>(&raw.w));
}

__device__ __forceinline__ void flush_pk(__half2* c2, float* a) {
#pragma unroll
    for (int j = 0; j < 4; ++j) {
        float2 f = __half22float2(c2[j]);
        a[2 * j] += f.x;
        a[2 * j + 1] += f.y;
        c2[j] = __float2half2_rn(0.f);
    }
}

// ---------------- Aggregation layer 1: wave per node ----------------
// 8 edge-groups x 8 lanes x 16B; 32-edge superblock = 4 gathers in flight,
// 16-edge remainder = 2-deep. fp16 chains <=4 adds then flush. h1 out fp16.

__global__ __launch_bounds__(256) void agg1_kernel(const __half* __restrict__ g1,
                                                   const int* __restrict__ row_off,
                                                   const int* __restrict__ deg,
                                                   const int* __restrict__ csr,
                                                   const float* __restrict__ dinv,
                                                   const float* __restrict__ b1,
                                                   __half* __restrict__ h1, int n) {
    int node = (blockIdx.x * 256 + threadIdx.x) >> 6;
    int lane = threadIdx.x & 63;
    int g = lane >> 3;        // edge group 0..7
    int f8 = lane & 7;        // 16B feature chunk 0..7
    if (node >= n) return;
    int start = row_off[node];
    int end = start + deg[node];
    float a[8];
#pragma unroll
    for (int j = 0; j < 8; ++j) a[j] = 0.f;
    if (g == 0)  // self loop counted once (f32 path)
        acc_row16(g1 + ((size_t)node << 6) + f8 * 8, a);
    __half2 c2[4];
#pragma unroll
    for (int j = 0; j < 4; ++j) c2[j] = __float2half2_rn(0.f);
    int e = start;
    for (; e + 32 <= end; e += 32) {  // 4 independent gathers in flight
        int i0 = csr[e + g];
        int i1 = csr[e + 8 + g];
        int i2 = csr[e + 16 + g];
        int i3 = csr[e + 24 + g];
        uint4 r0 = *reinterpret_cast<const uint4*>(g1 + ((size_t)i0 << 6) + f8 * 8);
        uint4 r1 = *reinterpret_cast<const uint4*>(g1 + ((size_t)i1 << 6) + f8 * 8);
        uint4 r2 = *reinterpret_cast<const uint4*>(g1 + ((size_t)i2 << 6) + f8 * 8);
        uint4 r3 = *reinterpret_cast<const uint4*>(g1 + ((size_t)i3 << 6) + f8 * 8);
        acc_pk_raw(r0, c2);
        acc_pk_raw(r1, c2);
        acc_pk_raw(r2, c2);
        acc_pk_raw(r3, c2);
        flush_pk(c2, a);  // <=4 fp16 adds per chain
    }
    if (e + 16 <= end) {  // 2-deep remainder
        int i0 = csr[e + g];
        int i1 = csr[e + 8 + g];
        uint4 r0 = *reinterpret_cast<const uint4*>(g1 + ((size_t)i0 << 6) + f8 * 8);
        uint4 r1 = *reinterpret_cast<const uint4*>(g1 + ((size_t)i1 << 6) + f8 * 8);
        acc_pk_raw(r0, c2);
        acc_pk_raw(r1, c2);
        e += 16;
    }
    if (e + 8 <= end) {
        int s = csr[e + g];
        uint4 r = *reinterpret_cast<const uint4*>(g1 + ((size_t)s << 6) + f8 * 8);
        acc_pk_raw(r, c2);
        e += 8;
    }
    if (e + g < end) {
        int s = csr[e + g];
        uint4 r = *reinterpret_cast<const uint4*>(g1 + ((size_t)s << 6) + f8 * 8);
        acc_pk_raw(r, c2);
    }
    flush_pk(c2, a);
    // fold 8 edge groups
#pragma unroll
    for (int j = 0; j < 8; ++j) a[j] += __shfl_xor(a[j], 8);
#pragma unroll
    for (int j = 0; j < 8; ++j) a[j] += __shfl_xor(a[j], 16);
#pragma unroll
    for (int j = 0; j < 8; ++j) a[j] += __shfl_xor(a[j], 32);
    if (g == 0) {
        float dn = dinv[node];
        float4 bl = *reinterpret_cast<const float4*>(b1 + f8 * 8);
        float4 bh = *reinterpret_cast<const float4*>(b1 + f8 * 8 + 4);
        __half hh[8];
        hh[0] = __float2half(fmaxf(a[0] * dn + bl.x, 0.f));
        hh[1] = __float2half(fmaxf(a[1] * dn + bl.y, 0.f));
        hh[2] = __float2half(fmaxf(a[2] * dn + bl.z, 0.f));
        hh[3] = __float2half(fmaxf(a[3] * dn + bl.w, 0.f));
        hh[4] = __float2half(fmaxf(a[4] * dn + bh.x, 0.f));
        hh[5] = __float2half(fmaxf(a[5] * dn + bh.y, 0.f));
        hh[6] = __float2half(fmaxf(a[6] * dn + bh.z, 0.f));
        hh[7] = __float2half(fmaxf(a[7] * dn + bh.w, 0.f));
        *reinterpret_cast<uint4*>(h1 + ((size_t)node << 6) + f8 * 8) =
            *reinterpret_cast<const uint4*>(hh);
    }
}

// ---------------- Aggregation layer 2 + pooling: HALF-wave per node ----------------

__global__ __launch_bounds__(256) void agg2_pool_kernel(const __half* __restrict__ g2,
                                                        const int* __restrict__ row_off,
                                                        const int* __restrict__ deg,
                                                        const int* __restrict__ csr,
                                                        const float* __restrict__ dinv,
                                                        const float* __restrict__ b2,
                                                        float* __restrict__ partials,
                                                        int nblocks, int n) {
    int tid = threadIdx.x;
    int half = tid >> 5;            // half-wave 0..7 in block
    int node = blockIdx.x * 8 + half;
    int l32 = tid & 31;
    int g = (l32 >> 2);             // edge group 0..7
    int f4 = l32 & 3;               // 16B feature chunk 0..3
    float a[8];
#pragma unroll
    for (int j = 0; j < 8; ++j) a[j] = 0.f;
    if (node < n) {
        int start = row_off[node];
        int end = start + deg[node];
        if (g == 0)
            acc_row16(g2 + ((size_t)node << 5) + f4 * 8, a);
        __half2 c2[4];
#pragma unroll
        for (int j = 0; j < 4; ++j) c2[j] = __float2half2_rn(0.f);
        int e = start;
        for (; e + 32 <= end; e += 32) {  // 4-deep
            int i0 = csr[e + g];
            int i1 = csr[e + 8 + g];
            int i2 = csr[e + 16 + g];
            int i3 = csr[e + 24 + g];
            uint4 r0 = *reinterpret_cast<const uint4*>(g2 + ((size_t)i0 << 5) + f4 * 8);
            uint4 r1 = *reinterpret_cast<const uint4*>(g2 + ((size_t)i1 << 5) + f4 * 8);
            uint4 r2 = *reinterpret_cast<const uint4*>(g2 + ((size_t)i2 << 5) + f4 * 8);
            uint4 r3 = *reinterpret_cast<const uint4*>(g2 + ((size_t)i3 << 5) + f4 * 8);
            acc_pk_raw(r0, c2);
            acc_pk_raw(r1, c2);
            acc_pk_raw(r2, c2);
            acc_pk_raw(r3, c2);
            flush_pk(c2, a);
        }
        if (e + 16 <= end) {  // 2-deep remainder
            int i0 = csr[e + g];
            int i1 = csr[e + 8 + g];
            uint4 r0 = *reinterpret_cast<const uint4*>(g2 + ((size_t)i0 << 5) + f4 * 8);
            uint4 r1 = *reinterpret_cast<const uint4*>(g2 + ((size_t)i1 << 5) + f4 * 8);
            acc_pk_raw(r0, c2);
            acc_pk_raw(r1, c2);
            e += 16;
        }
        if (e + 8 <= end) {
            int s = csr[e + g];
            uint4 r = *reinterpret_cast<const uint4*>(g2 + ((size_t)s << 5) + f4 * 8);
            acc_pk_raw(r, c2);
            e += 8;
        }
        if (e + g < end) {
            int s = csr[e + g];
            uint4 r = *reinterpret_cast<const uint4*>(g2 + ((size_t)s << 5) + f4 * 8);
            acc_pk_raw(r, c2);
        }
        flush_pk(c2, a);
        // fold 8 edge groups within the half-wave
#pragma unroll
        for (int j = 0; j < 8; ++j) a[j] += __shfl_xor(a[j], 4);
#pragma unroll
        for (int j = 0; j < 8; ++j) a[j] += __shfl_xor(a[j], 8);
#pragma unroll
        for (int j = 0; j < 8; ++j) a[j] += __shfl_xor(a[j], 16);
    }
    __shared__ float sdata[8][32];
    if (g == 0) {
        float relu[8];
        if (node < n) {
            float dn = dinv[node];
#pragma unroll
            for (int j = 0; j < 8; ++j)
                relu[j] = fmaxf(a[j] * dn + b2[f4 * 8 + j], 0.f);
        } else {
#pragma unroll
            for (int j = 0; j < 8; ++j) relu[j] = 0.f;
        }
#pragma unroll
        for (int j = 0; j < 8; ++j) sdata[half][f4 * 8 + j] = relu[j];
    }
    __syncthreads();
    if (tid < 32) {
        float s = 0.f;
#pragma unroll
        for (int r = 0; r < 8; ++r) s += sdata[r][tid];
        partials[tid * nblocks + blockIdx.x] = s;
    }
}

// 32 blocks, one per feature; fused FC: atomicAdd into pre-zeroed out[0].
__global__ __launch_bounds__(256) void reduce_fc_kernel(const float* __restrict__ partials,
                                                        int nblocks,
                                                        const float* __restrict__ fcw,
                                                        const float* __restrict__ fcb,
                                                        float* __restrict__ out, int n) {
    int f = blockIdx.x;
    const float* col = partials + (size_t)f * nblocks;
    float s = 0.f;
    for (int i = threadIdx.x; i < nblocks; i += 256) s += col[i];
    __shared__ float red[256];
    red[threadIdx.x] = s;
    __syncthreads();
    for (int ofs = 128; ofs > 0; ofs >>= 1) {
        if (threadIdx.x < ofs) red[threadIdx.x] += red[threadIdx.x + ofs];
        __syncthreads();
    }
    if (threadIdx.x == 0) {
        float v = (float)((double)red[0] / (double)n * (double)fcw[f]);
        if (f == 0) v += fcb[0];
        atomicAdd(out, v);
    }
}

// ---------------- launch ----------------

extern "C" void kernel_launch(void* const* d_in, const int* in_sizes, int n_in,
                              void* d_out, int out_size, void* d_ws, size_t ws_size,
                              hipStream_t stream) {
    const float* x   = (const float*)d_in[0];
    const int*   ei  = (const int*)d_in[1];
    const float* W1  = (const float*)d_in[2];
    const float* b1  = (const float*)d_in[3];
    const float* W2  = (const float*)d_in[4];
    const float* b2  = (const float*)d_in[5];
    const float* fcw = (const float*)d_in[6];
    const float* fcb = (const float*)d_in[7];
    float* out = (float*)d_out;

    const int N = in_sizes[0] / 256;  // 100000
    const int E = in_sizes[1] / 2;    // 3200000
    const int* src = ei;
    const int* dst = ei + E;

    const int NB = (N + BNODES - 1) >> BSH;            // 782 buckets
    const int CH = (((E + NBLK - 1) / NBLK) + 3) & ~3; // edges/block, x4 aligned (6252)
    const int nb2 = (N + 7) / 8;                       // agg2 blocks (8 nodes)
    const size_t CAPTOT = (size_t)NB * CAP;            // fixed-capacity layout size

    char* ws = (char*)d_ws;
    size_t off = 0;
    auto alloc = [&](size_t bytes) -> void* {
        void* p = ws + off;
        off = (off + bytes + 255) & ~(size_t)255;
        return p;
    };
    int*   cnt      = (int*)alloc((size_t)NB * 4);
    int*   row_off  = (int*)alloc((size_t)N * 4);
    int*   deg      = (int*)alloc((size_t)N * 4);
    float* dinv     = (float*)alloc((size_t)N * 4);
    int*   csr      = (int*)alloc(CAPTOT * 4);
    __half* W1t     = (__half*)alloc((size_t)64 * 256 * 2);
    __half* W2t     = (__half*)alloc((size_t)32 * 64 * 2);
    // region P: buck (CAPTOT int) aliases g1 (N*F1 halves) — buck dead before gemm1
    size_t szP = CAPTOT * 4;
    size_t szG1 = (size_t)N * F1 * 2;
    void* P = alloc(szP > szG1 ? szP : szG1);
    int*    buck = (int*)P;
    __half* g1   = (__half*)P;
    __half* h1      = (__half*)alloc((size_t)N * F1 * 2);
    __half* g2      = (__half*)alloc((size_t)N * F2 * 2);
    float* partials = (float*)alloc((size_t)F2 * nb2 * 4);

    // ---- CSR build: 3 kernels (prep0, fused sorted scatter, deg/fill) ----
    prep0_kernel<<<1, 256, 0, stream>>>(out, cnt, NB);
    scatter_sorted3<<<NBLK + 1, 256, 0, stream>>>(src, dst, cnt, buck, W1, W2, W1t, W2t, E, CH, NB);
    bucket_deg_fill2<<<NB, 256, 0, stream>>>(buck, cnt, deg, dinv, row_off, csr, N, NB);

    int nbG = (N + 63) / 64;  // 1563
    // ---- layer 1 ----
    gemm_mfma_kernel<true, 256, 64><<<nbG, 256, 0, stream>>>(x, W1t, dinv, g1, N);
    agg1_kernel<<<(N + 3) / 4, 256, 0, stream>>>(g1, row_off, deg, csr, dinv, b1, h1, N);

    // ---- layer 2 ----
    gemm_mfma_kernel<false, 64, 32><<<nbG, 256, 0, stream>>>(h1, W2t, dinv, g2, N);
    agg2_pool_kernel<<<nb2, 256, 0, stream>>>(g2, row_off, deg, csr, dinv, b2, partials, nb2, N);

    reduce_fc_kernel<<<F2, 256, 0, stream>>>(partials, nb2, fcw, fcb, out, N);
}